// Round 1
// baseline (15298.683 us; speedup 1.0000x reference)
//
#include <hip/hip_runtime.h>
#include <math.h>

#define DIV_UP(a,b) (((a)+(b)-1)/(b))

// ---------------------------------------------------------------------------
// Generic strided fp32 GEMM: C[z, m, n] = alpha * sum_k A[z,m,k] * B[z,k,n] + bias[n]
// A element addr: a_off + z*a_bs + m*sam + k*sak
// B element addr: b_off + z*b_bs + k*sbk + n*sbn
// C element addr: c_off + z*c_bs + m*ldc + n   (row-major)
// 64x64 tile, K-chunk 16, 256 threads, 4x4 microtile.
// ---------------------------------------------------------------------------
__global__ __launch_bounds__(256) void gemm_strided(
    const float* __restrict__ A, const float* __restrict__ B, float* __restrict__ C,
    int M, int N, int K,
    long long a_off, int sam, int sak, long long a_bs,
    long long b_off, int sbk, int sbn, long long b_bs,
    long long c_off, int ldc, long long c_bs,
    float alpha, const float* __restrict__ bias)
{
    __shared__ float As[16][68];
    __shared__ float Bs[16][68];
    const int t = threadIdx.x;
    const int n0 = blockIdx.x * 64;
    const int m0 = blockIdx.y * 64;
    const int z = blockIdx.z;
    const float* Ab = A + a_off + (long long)z * a_bs;
    const float* Bb = B + b_off + (long long)z * b_bs;
    const int tx = t & 15, ty = t >> 4;
    float acc[4][4] = {};

    for (int kt = 0; kt < K; kt += 16) {
        // ---- stage A tile (16k x 64m) ----
        if (sak == 1) {
            // K-contiguous rows: each thread loads 4 consecutive k for one m
            int mm = t >> 2;
            int kq = (t & 3) * 4;
            int m = m0 + mm;
            if (m < M) {
                // sam % 4 == 0 for all call sites -> 16B aligned
                float4 v = *(const float4*)(Ab + (long long)m * sam + (kt + kq));
                As[kq + 0][mm] = v.x; As[kq + 1][mm] = v.y;
                As[kq + 2][mm] = v.z; As[kq + 3][mm] = v.w;
            } else {
                As[kq + 0][mm] = 0.f; As[kq + 1][mm] = 0.f;
                As[kq + 2][mm] = 0.f; As[kq + 3][mm] = 0.f;
            }
        } else {
            // M-contiguous (or generic): lanes along m
            int mm = t & 63;
            int kb = t >> 6;
            int m = m0 + mm;
            #pragma unroll
            for (int e = 0; e < 4; ++e) {
                int kk = kb + e * 4;
                int k = kt + kk;
                float v = 0.f;
                if (m < M) v = Ab[(long long)m * sam + (long long)k * sak];
                As[kk][mm] = v;
            }
        }
        // ---- stage B tile (16k x 64n) ----
        if (sbn == 1) {
            // lanes along n: coalesced
            int nn = t & 63;
            int kb = t >> 6;
            int n = n0 + nn;
            #pragma unroll
            for (int e = 0; e < 4; ++e) {
                int kk = kb + e * 4;
                int k = kt + kk;
                float v = 0.f;
                if (n < N) v = Bb[(long long)k * sbk + n];
                Bs[kk][nn] = v;
            }
        } else {
            // sbk == 1 at all such call sites: 4 consecutive k per thread
            int nn = t >> 2;
            int kq = (t & 3) * 4;
            int n = n0 + nn;
            if (n < N) {
                float4 v = *(const float4*)(Bb + (long long)n * sbn + (kt + kq));
                Bs[kq + 0][nn] = v.x; Bs[kq + 1][nn] = v.y;
                Bs[kq + 2][nn] = v.z; Bs[kq + 3][nn] = v.w;
            } else {
                Bs[kq + 0][nn] = 0.f; Bs[kq + 1][nn] = 0.f;
                Bs[kq + 2][nn] = 0.f; Bs[kq + 3][nn] = 0.f;
            }
        }
        __syncthreads();
        #pragma unroll
        for (int kk = 0; kk < 16; ++kk) {
            float a[4], b[4];
            *(float4*)a = *(const float4*)&As[kk][ty * 4];
            *(float4*)b = *(const float4*)&Bs[kk][tx * 4];
            #pragma unroll
            for (int i = 0; i < 4; ++i)
                #pragma unroll
                for (int j = 0; j < 4; ++j)
                    acc[i][j] = fmaf(a[i], b[j], acc[i][j]);
        }
        __syncthreads();
    }
    // ---- epilogue ----
    float bb[4];
    #pragma unroll
    for (int j = 0; j < 4; ++j) {
        int n = n0 + tx * 4 + j;
        bb[j] = (bias && n < N) ? bias[n] : 0.f;
    }
    float* Cb = C + c_off + (long long)z * c_bs;
    #pragma unroll
    for (int i = 0; i < 4; ++i) {
        int m = m0 + ty * 4 + i;
        if (m >= M) continue;
        int n = n0 + tx * 4;
        if (n + 3 < N) {
            float4 v;
            v.x = alpha * acc[i][0] + bb[0];
            v.y = alpha * acc[i][1] + bb[1];
            v.z = alpha * acc[i][2] + bb[2];
            v.w = alpha * acc[i][3] + bb[3];
            *(float4*)(Cb + (long long)m * ldc + n) = v;
        } else {
            #pragma unroll
            for (int j = 0; j < 4; ++j)
                if (n + j < N) Cb[(long long)m * ldc + n + j] = alpha * acc[i][j] + bb[j];
        }
    }
}

// ---------------------------------------------------------------------------
// conv3x3 pad=1 as implicit GEMM. in: (Cin,H,W), w: OIHW (Cout,Cin,3,3),
// out: (Cout,H,W). Epilogue: v = acc*scale[n] + bias[n] (scale null -> 1),
// optional residual add (same layout as out), optional relu.
// ---------------------------------------------------------------------------
__global__ __launch_bounds__(256) void conv3x3(
    const float* __restrict__ in, const float* __restrict__ w,
    const float* __restrict__ bias, const float* __restrict__ scale,
    const float* __restrict__ resid, int do_relu,
    float* __restrict__ out, int Cin, int Cout, int H, int W)
{
    const int M = H * W;
    const int K = Cin * 9;
    __shared__ float As[16][68];
    __shared__ float Bs[16][68];
    const int t = threadIdx.x;
    const int n0 = blockIdx.x * 64;
    const int m0 = blockIdx.y * 64;
    const int tx = t & 15, ty = t >> 4;

    // A staging: fixed m per thread (mm = t&63), 4 k-planes (kb + 4e)
    const int mm = t & 63;
    const int kb = t >> 6;
    const int m = m0 + mm;
    const int hh = m / W;
    const int ww = m - hh * W;
    const bool mok = (m < M);

    // B staging: 4 consecutive k for one n
    const int nn_b = t >> 2;
    const int kq_b = (t & 3) * 4;
    const float* wrow = w + (long long)(n0 + nn_b) * K;

    float acc[4][4] = {};

    for (int kt = 0; kt < K; kt += 16) {
        #pragma unroll
        for (int e = 0; e < 4; ++e) {
            int kk = kb + e * 4;
            int k = kt + kk;
            int ci = k / 9;
            int r = k - ci * 9;
            int kh = r / 3;
            int kw = r - kh * 3;
            int ih = hh + kh - 1;
            int iw = ww + kw - 1;
            float v = 0.f;
            if (mok && (unsigned)ih < (unsigned)H && (unsigned)iw < (unsigned)W)
                v = in[ci * M + ih * W + iw];
            As[kk][mm] = v;
        }
        {
            float4 v = *(const float4*)(wrow + kt + kq_b);
            Bs[kq_b + 0][nn_b] = v.x; Bs[kq_b + 1][nn_b] = v.y;
            Bs[kq_b + 2][nn_b] = v.z; Bs[kq_b + 3][nn_b] = v.w;
        }
        __syncthreads();
        #pragma unroll
        for (int kk = 0; kk < 16; ++kk) {
            float a[4], b[4];
            *(float4*)a = *(const float4*)&As[kk][ty * 4];
            *(float4*)b = *(const float4*)&Bs[kk][tx * 4];
            #pragma unroll
            for (int i = 0; i < 4; ++i)
                #pragma unroll
                for (int j = 0; j < 4; ++j)
                    acc[i][j] = fmaf(a[i], b[j], acc[i][j]);
        }
        __syncthreads();
    }

    // epilogue: out[n*M + m], vectorize along m
    #pragma unroll
    for (int j = 0; j < 4; ++j) {
        int n = n0 + tx * 4 + j;    // always < Cout (Cout % 64 == 0)
        float sc = scale ? scale[n] : 1.f;
        float bi = bias ? bias[n] : 0.f;
        int mo = m0 + ty * 4;
        long long base = (long long)n * M + mo;
        if (mo + 3 < M) {
            float4 v;
            v.x = acc[0][j] * sc + bi;
            v.y = acc[1][j] * sc + bi;
            v.z = acc[2][j] * sc + bi;
            v.w = acc[3][j] * sc + bi;
            if (resid) {
                float4 r = *(const float4*)(resid + base);
                v.x += r.x; v.y += r.y; v.z += r.z; v.w += r.w;
            }
            if (do_relu) {
                v.x = fmaxf(v.x, 0.f); v.y = fmaxf(v.y, 0.f);
                v.z = fmaxf(v.z, 0.f); v.w = fmaxf(v.w, 0.f);
            }
            *(float4*)(out + base) = v;
        } else {
            #pragma unroll
            for (int i = 0; i < 4; ++i) {
                if (mo + i >= M) continue;
                float v = acc[i][j] * sc + bi;
                if (resid) v += resid[base + i];
                if (do_relu) v = fmaxf(v, 0.f);
                out[base + i] = v;
            }
        }
    }
}

// ---------------------------------------------------------------------------
// softmax over rows of length 1024 (in-place). One 256-thread block per row.
// ---------------------------------------------------------------------------
__global__ __launch_bounds__(256) void softmax1024(float* __restrict__ S)
{
    __shared__ float red[4];
    float* p = S + (long long)blockIdx.x * 1024;
    const int t = threadIdx.x;
    float4 v = *(float4*)(p + t * 4);
    float mx = fmaxf(fmaxf(v.x, v.y), fmaxf(v.z, v.w));
    #pragma unroll
    for (int o = 32; o > 0; o >>= 1) mx = fmaxf(mx, __shfl_down(mx, o));
    if ((t & 63) == 0) red[t >> 6] = mx;
    __syncthreads();
    float m4 = fmaxf(fmaxf(red[0], red[1]), fmaxf(red[2], red[3]));
    v.x = expf(v.x - m4); v.y = expf(v.y - m4);
    v.z = expf(v.z - m4); v.w = expf(v.w - m4);
    float sm = v.x + v.y + v.z + v.w;
    #pragma unroll
    for (int o = 32; o > 0; o >>= 1) sm += __shfl_down(sm, o);
    __syncthreads();
    if ((t & 63) == 0) red[t >> 6] = sm;
    __syncthreads();
    float inv = 1.f / (red[0] + red[1] + red[2] + red[3]);
    v.x *= inv; v.y *= inv; v.z *= inv; v.w *= inv;
    *(float4*)(p + t * 4) = v;
}

// x[c,n] += p[n,c]  (C=512, N=1024)
__global__ __launch_bounds__(256) void add_xpose(float* __restrict__ x, const float* __restrict__ p)
{
    int idx = blockIdx.x * 256 + threadIdx.x;   // 524288
    int n = idx >> 9;
    int c = idx & 511;
    x[c * 1024 + n] += p[idx];
}

__global__ __launch_bounds__(256) void copyk(float* __restrict__ dst, const float* __restrict__ src, int n4)
{
    int idx = blockIdx.x * 256 + threadIdx.x;
    if (idx < n4) ((float4*)dst)[idx] = ((const float4*)src)[idx];
}

// nearest grid_sample 32x32 -> 50x50 (align_corners=False, zeros padding)
__global__ __launch_bounds__(256) void grid_sample_nn(const float* __restrict__ x, float* __restrict__ xs)
{
    int idx = blockIdx.x * 256 + threadIdx.x;    // 512*50*50
    if (idx >= 512 * 50 * 50) return;
    int j = idx % 50;
    int tmp = idx / 50;
    int i = tmp % 50;
    int c = tmp / 50;
    float vy = -49.f + 2.f * i;
    float gy = (vy + 51.2f) / 102.4f * 2.f - 1.f;
    float fy = ((gy + 1.f) * 32.f - 1.f) * 0.5f;
    int iy = (int)roundf(fy);
    bool oky = (iy >= 0) && (iy < 32);
    iy = min(max(iy, 0), 31);
    float vx = -49.f + 2.f * j;
    float gx = (vx + 51.2f) / 102.4f * 2.f - 1.f;
    float fx = ((gx + 1.f) * 32.f - 1.f) * 0.5f;
    int ix = (int)roundf(fx);
    bool okx = (ix >= 0) && (ix < 32);
    ix = min(max(ix, 0), 31);
    float v = (oky && okx) ? x[c * 1024 + iy * 32 + ix] : 0.f;
    xs[idx] = v;
}

// pixel shuffle r=2: up (2048,50,50) -> u (512,100,100)
__global__ __launch_bounds__(256) void pixshuf(const float* __restrict__ up, float* __restrict__ u)
{
    int idx = blockIdx.x * 256 + threadIdx.x;    // 512*100*100
    if (idx >= 512 * 100 * 100) return;
    int ow = idx % 100;
    int tmp = idx / 100;
    int oh = tmp % 100;
    int c = tmp / 100;
    int h = oh >> 1, r1 = oh & 1;
    int w = ow >> 1, r2 = ow & 1;
    u[idx] = up[(c * 4 + r1 * 2 + r2) * 2500 + h * 50 + w];
}

// fold BN (eval) into per-channel scale/bias for two BNs
__global__ __launch_bounds__(256) void bnprep(
    const float* g1, const float* b1, const float* m1, const float* v1,
    const float* g2, const float* b2, const float* m2, const float* v2,
    float* sc1, float* bi1, float* sc2, float* bi2)
{
    int c = blockIdx.x * 256 + threadIdx.x;
    if (c >= 512) return;
    float s1 = g1[c] * rsqrtf(v1[c] + 1e-5f);
    sc1[c] = s1; bi1[c] = b1[c] - m1[c] * s1;
    float s2 = g2[c] * rsqrtf(v2[c] + 1e-5f);
    sc2[c] = s2; bi2[c] = b2[c] - m2[c] * s2;
}

// 1x1 conv (512 -> 6) + sigmoid. in (512,100,100), out (6,100,100)
__global__ __launch_bounds__(256) void conv1x1_sig(
    const float* __restrict__ in, const float* __restrict__ w,
    const float* __restrict__ b, float* __restrict__ out)
{
    int idx = blockIdx.x * 256 + threadIdx.x;   // 60000
    if (idx >= 60000) return;
    int m = idx % 10000;
    int co = idx / 10000;
    float s = b[co];
    const float* wr = w + co * 512;
    for (int ci = 0; ci < 512; ++ci)
        s = fmaf(in[ci * 10000 + m], wr[ci], s);
    out[idx] = 1.f / (1.f + expf(-s));
}

// ---------------------------------------------------------------------------
extern "C" void kernel_launch(void* const* d_in, const int* in_sizes, int n_in,
                              void* d_out, int out_size, void* d_ws, size_t ws_size,
                              hipStream_t stream)
{
    const float* x      = (const float*)d_in[0];
    const float* qkv_w  = (const float*)d_in[1];
    const float* proj_w = (const float*)d_in[2];
    const float* proj_b = (const float*)d_in[3];
    const float* head_w = (const float*)d_in[4];
    const float* head_b = (const float*)d_in[5];
    const float* body_w = (const float*)d_in[6];
    const float* body_b = (const float*)d_in[7];
    const float* btail_w= (const float*)d_in[8];
    const float* btail_b= (const float*)d_in[9];
    const float* up_w   = (const float*)d_in[10];
    const float* up_b   = (const float*)d_in[11];
    const float* tail_w = (const float*)d_in[12];
    const float* tail_b = (const float*)d_in[13];
    const float* c1_w   = (const float*)d_in[14];
    const float* bn1_g  = (const float*)d_in[15];
    const float* bn1_b  = (const float*)d_in[16];
    const float* bn1_m  = (const float*)d_in[17];
    const float* bn1_v  = (const float*)d_in[18];
    const float* c2_w   = (const float*)d_in[19];
    const float* bn2_g  = (const float*)d_in[20];
    const float* bn2_b  = (const float*)d_in[21];
    const float* bn2_m  = (const float*)d_in[22];
    const float* bn2_v  = (const float*)d_in[23];
    const float* c3_w   = (const float*)d_in[24];
    const float* c3_b   = (const float*)d_in[25];

    float* ws = (float*)d_ws;
    // attention phase arena
    float* XBUF = ws + 0;          // 512*1024
    float* QKV  = ws + 524288;     // 1024*1536
    float* S    = ws + 2097152;    // 8*1024*1024
    float* RES  = ws + 10485760;   // 1024*512
    float* P    = ws + 11010048;   // 1024*512
    // conv phase arena (aliases attention buffers — all dead by then)
    float* XS   = ws + 524288;     // 512*2500
    float* Hh   = ws + 2097152;    // 512*2500
    float* T_   = ws + 3377152;    // 512*2500
    float* R_   = ws + 4657152;    // 512*2500
    float* R2   = ws + 5937152;    // 512*2500
    float* UP   = ws + 7217152;    // 2048*2500
    float* U_   = ws + 0;          // 512*10000 (aliases XBUF/XS/H/T/R — dead)
    float* Y_   = ws + 7217152;    // 512*10000 (aliases UP — dead after shuffle)
    float* Z1   = ws + 0;          // 512*10000 (aliases U — dead after tail... c1 input is Y)
    float* Z2   = ws + 5120000;    // 512*10000
    float* SC1  = ws + 12337152;
    float* BI1  = SC1 + 512;
    float* SC2  = BI1 + 512;
    float* BI2  = SC2 + 512;

    const float scale = 0.044194173824159216f;  // 512^-0.5

    // x -> workspace (attention updates it in place)
    copyk<<<512, 256, 0, stream>>>(XBUF, x, 131072);

    for (int i = 0; i < 8; ++i) {
        // qkv = t @ qkv_w[i] : M=1024 N=1536 K=512 ; A[m,k]=XBUF[k*1024+m]
        gemm_strided<<<dim3(24, 16, 1), 256, 0, stream>>>(
            XBUF, qkv_w, QKV, 1024, 1536, 512,
            0LL, 1, 1024, 0LL,
            (long long)i * 512 * 1536, 1536, 1, 0LL,
            0LL, 1536, 0LL, 1.f, nullptr);
        // scores: per head z: S[z,n,m] = scale * q.k ; A[m,k]=QKV[m*1536+z*64+k]
        gemm_strided<<<dim3(16, 16, 8), 256, 0, stream>>>(
            QKV, QKV, S, 1024, 1024, 64,
            0LL, 1536, 1, 64LL,
            512LL, 1, 1536, 64LL,
            0LL, 1024, 1048576LL, scale, nullptr);
        softmax1024<<<8192, 256, 0, stream>>>(S);
        // PV: RES[m, z*64+n] = sum_k S[z,m,k] * V[z,k,n]
        gemm_strided<<<dim3(1, 16, 8), 256, 0, stream>>>(
            S, QKV, RES, 1024, 64, 1024,
            0LL, 1024, 1, 1048576LL,
            1024LL, 1536, 1, 64LL,
            0LL, 512, 64LL, 1.f, nullptr);
        // proj: P = RES @ proj_w[i] + proj_b[i]
        gemm_strided<<<dim3(8, 16, 1), 256, 0, stream>>>(
            RES, proj_w, P, 1024, 512, 512,
            0LL, 512, 1, 0LL,
            (long long)i * 512 * 512, 512, 1, 0LL,
            0LL, 512, 0LL, 1.f, proj_b + i * 512);
        add_xpose<<<2048, 256, 0, stream>>>(XBUF, P);
    }

    // BEV grid transform (nearest, all in-bounds)
    grid_sample_nn<<<DIV_UP(1280000, 256), 256, 0, stream>>>(XBUF, XS);

    // EDSR
    conv3x3<<<dim3(8, 40), 256, 0, stream>>>(XS, head_w, head_b, nullptr, nullptr, 0, Hh, 512, 512, 50, 50);
    for (int i = 0; i < 8; ++i) {
        const float* rin = (i == 0) ? Hh : R_;
        conv3x3<<<dim3(8, 40), 256, 0, stream>>>(rin, body_w + (long long)(2 * i) * 2359296,
                                                 body_b + 2 * i * 512, nullptr, nullptr, 1, T_, 512, 512, 50, 50);
        conv3x3<<<dim3(8, 40), 256, 0, stream>>>(T_, body_w + (long long)(2 * i + 1) * 2359296,
                                                 body_b + (2 * i + 1) * 512, nullptr, rin, 0, R_, 512, 512, 50, 50);
    }
    conv3x3<<<dim3(8, 40), 256, 0, stream>>>(R_, btail_w, btail_b, nullptr, Hh, 0, R2, 512, 512, 50, 50);
    conv3x3<<<dim3(32, 40), 256, 0, stream>>>(R2, up_w, up_b, nullptr, nullptr, 0, UP, 512, 2048, 50, 50);
    pixshuf<<<DIV_UP(5120000, 256), 256, 0, stream>>>(UP, U_);
    conv3x3<<<dim3(8, 157), 256, 0, stream>>>(U_, tail_w, tail_b, nullptr, nullptr, 0, Y_, 512, 512, 100, 100);

    // classifier
    bnprep<<<2, 256, 0, stream>>>(bn1_g, bn1_b, bn1_m, bn1_v, bn2_g, bn2_b, bn2_m, bn2_v, SC1, BI1, SC2, BI2);
    conv3x3<<<dim3(8, 157), 256, 0, stream>>>(Y_, c1_w, BI1, SC1, nullptr, 1, Z1, 512, 512, 100, 100);
    conv3x3<<<dim3(8, 157), 256, 0, stream>>>(Z1, c2_w, BI2, SC2, nullptr, 1, Z2, 512, 512, 100, 100);
    conv1x1_sig<<<DIV_UP(60000, 256), 256, 0, stream>>>(Z2, c3_w, c3_b, (float*)d_out);
}

// Round 3
// 6551.109 us; speedup vs baseline: 2.3353x; 2.3353x over previous
//
#include <hip/hip_runtime.h>
#include <math.h>

#define DIV_UP(a,b) (((a)+(b)-1)/(b))

typedef __bf16 bf16x8 __attribute__((ext_vector_type(8)));
typedef float floatx4 __attribute__((ext_vector_type(4)));

__device__ __forceinline__ unsigned short f2bf(float f) {
    unsigned u = __builtin_bit_cast(unsigned, f);
    u = (u + 0x7fffu + ((u >> 16) & 1u)) >> 16;
    return (unsigned short)u;
}
__device__ __forceinline__ float bf2f(unsigned short h) {
    unsigned u = ((unsigned)h) << 16;
    return __builtin_bit_cast(float, u);
}

// async global->LDS, 16B per lane (dest = wave-uniform base + lane*16)
__device__ __forceinline__ void gll16(const void* g, void* l) {
    __builtin_amdgcn_global_load_lds(
        (const __attribute__((address_space(1))) void*)g,
        (__attribute__((address_space(3))) void*)l, 16, 0, 0);
}

// ---------------------------------------------------------------------------
// Split-bf16 NT GEMM (fp32-accurate): C = alpha*sum_k A[m][k]*B[n][k] + epi.
// A approx Ah+Al, B approx Bh+Bl (bf16 hi/lo pairs, k-contig rows).
// acc += Ah*Bh + Ah*Bl + Al*Bh  (3 MFMAs; Al*Bl ~2^-16 rel, dropped).
// Epilogue: t = acc*alpha; t = t*scale_m[m] + bias_m[m] + bias_n[n] + resid;
//           relu; C (f32) and/or (Ch,Cl) bf16 hi/lo outputs.
// ---------------------------------------------------------------------------
template<int BM, int BN, int GWM, int GWN>
__global__ __launch_bounds__(256) void gemm3_nt(
    const unsigned short* __restrict__ Ah, const unsigned short* __restrict__ Al,
    int lda, long long a_bs,
    const unsigned short* __restrict__ Bh, const unsigned short* __restrict__ Bl,
    int ldb, long long b_bs,
    float* C, unsigned short* Ch, unsigned short* Cl, int ldc, long long c_bs,
    const float* resid, int M, int N, int K, float alpha,
    const float* __restrict__ bias_m, const float* __restrict__ scale_m,
    const float* __restrict__ bias_n, int relu)
{
    constexpr int WTM = BM / GWM, WTN = BN / GWN;
    constexpr int TM = WTM / 16, TN = WTN / 16;
    __shared__ unsigned short Ash[BM * 32];
    __shared__ unsigned short Asl[BM * 32];
    __shared__ unsigned short Bsh[BN * 32];
    __shared__ unsigned short Bsl[BN * 32];
    const int tid = threadIdx.x;
    const int lane = tid & 63;
    const int w = tid >> 6;
    const int wm = (w % GWM) * WTM, wn = (w / GWM) * WTN;
    const int m0 = blockIdx.y * BM, n0 = blockIdx.x * BN;
    const int z = blockIdx.z;
    const unsigned short* Ahb = Ah + (long long)z * a_bs;
    const unsigned short* Alb = Al + (long long)z * a_bs;
    const unsigned short* Bhb = Bh + (long long)z * b_bs;
    const unsigned short* Blb = Bl + (long long)z * b_bs;
    const int quad = lane >> 4;

    floatx4 acc[TM][TN];
    #pragma unroll
    for (int i = 0; i < TM; ++i)
        #pragma unroll
        for (int j = 0; j < TN; ++j)
            #pragma unroll
            for (int r = 0; r < 4; ++r) acc[i][j][r] = 0.f;

    for (int kt = 0; kt < K; kt += 32) {
        #pragma unroll
        for (int p = 0; p < BM / 64; ++p) {
            int idx = p * 256 + tid;
            int row = idx >> 2;
            int olog = (idx & 3) ^ ((row >> 1) & 3);
            int gr = m0 + row; if (gr > M - 1) gr = M - 1;
            long long go = (long long)gr * lda + kt + olog * 8;
            gll16(Ahb + go, &Ash[idx * 8]);
            gll16(Alb + go, &Asl[idx * 8]);
        }
        #pragma unroll
        for (int p = 0; p < BN / 64; ++p) {
            int idx = p * 256 + tid;
            int row = idx >> 2;
            int olog = (idx & 3) ^ ((row >> 1) & 3);
            int gr = n0 + row; if (gr > N - 1) gr = N - 1;
            long long go = (long long)gr * ldb + kt + olog * 8;
            gll16(Bhb + go, &Bsh[idx * 8]);
            gll16(Blb + go, &Bsl[idx * 8]);
        }
        __syncthreads();

        bf16x8 afh[TM], afl[TM], bfh[TN], bfl[TN];
        #pragma unroll
        for (int i = 0; i < TM; ++i) {
            int row = wm + i * 16 + (lane & 15);
            int oph = quad ^ ((row >> 1) & 3);
            afh[i] = *(const bf16x8*)&Ash[row * 32 + oph * 8];
            afl[i] = *(const bf16x8*)&Asl[row * 32 + oph * 8];
        }
        #pragma unroll
        for (int j = 0; j < TN; ++j) {
            int row = wn + j * 16 + (lane & 15);
            int oph = quad ^ ((row >> 1) & 3);
            bfh[j] = *(const bf16x8*)&Bsh[row * 32 + oph * 8];
            bfl[j] = *(const bf16x8*)&Bsl[row * 32 + oph * 8];
        }
        #pragma unroll
        for (int i = 0; i < TM; ++i)
            #pragma unroll
            for (int j = 0; j < TN; ++j) {
                acc[i][j] = __builtin_amdgcn_mfma_f32_16x16x32_bf16(afh[i], bfl[j], acc[i][j], 0, 0, 0);
                acc[i][j] = __builtin_amdgcn_mfma_f32_16x16x32_bf16(afl[i], bfh[j], acc[i][j], 0, 0, 0);
                acc[i][j] = __builtin_amdgcn_mfma_f32_16x16x32_bf16(afh[i], bfh[j], acc[i][j], 0, 0, 0);
            }
        __syncthreads();
    }

    #pragma unroll
    for (int i = 0; i < TM; ++i) {
        int mbase = m0 + wm + i * 16 + quad * 4;
        #pragma unroll
        for (int j = 0; j < TN; ++j) {
            int n = n0 + wn + j * 16 + (lane & 15);
            if (n >= N) continue;
            float bn_ = bias_n ? bias_n[n] : 0.f;
            #pragma unroll
            for (int r = 0; r < 4; ++r) {
                int m = mbase + r;
                if (m >= M) continue;
                float t = acc[i][j][r] * alpha;
                if (scale_m) t *= scale_m[m];
                if (bias_m)  t += bias_m[m];
                t += bn_;
                long long idx = (long long)z * c_bs + (long long)m * ldc + n;
                if (resid) t += resid[idx];
                if (relu) t = fmaxf(t, 0.f);
                if (C)  C[idx] = t;
                if (Ch) {
                    unsigned short h = f2bf(t);
                    Ch[idx] = h;
                    Cl[idx] = f2bf(t - bf2f(h));
                }
            }
        }
    }
}

// ---------------------------------------------------------------------------
// im2col, split output: col[p-pix0][ci*9 + (dh+1)*3 + (dw+1)] -> hi/lo
// ---------------------------------------------------------------------------
__global__ __launch_bounds__(256) void im2col2(const float* __restrict__ in,
                                               unsigned short* __restrict__ colh,
                                               unsigned short* __restrict__ coll,
                                               int H, int W, int pix0)
{
    const int p = pix0 + blockIdx.x;
    const int h = p / W, w = p - h * W;
    unsigned short* rh = colh + (long long)blockIdx.x * 4608;
    unsigned short* rl = coll + (long long)blockIdx.x * 4608;
    for (int k = threadIdx.x; k < 4608; k += 256) {
        int ci = k / 9, r = k - ci * 9;
        int dh = r / 3 - 1, dw = r - (r / 3) * 3 - 1;
        int ih = h + dh, iw = w + dw;
        float v = ((unsigned)ih < (unsigned)H && (unsigned)iw < (unsigned)W)
                      ? in[(long long)ci * H * W + ih * W + iw] : 0.f;
        unsigned short hh = f2bf(v);
        rh[k] = hh;
        rl[k] = f2bf(v - bf2f(hh));
    }
}

// flat fp32 -> bf16 hi/lo
__global__ __launch_bounds__(256) void castbf2(const float* __restrict__ s,
                                               unsigned short* __restrict__ dh,
                                               unsigned short* __restrict__ dl, int n4)
{
    int i = blockIdx.x * 256 + threadIdx.x;
    if (i >= n4) return;
    float4 v = ((const float4*)s)[i];
    ushort4 oh, ol;
    oh.x = f2bf(v.x); ol.x = f2bf(v.x - bf2f(oh.x));
    oh.y = f2bf(v.y); ol.y = f2bf(v.y - bf2f(oh.y));
    oh.z = f2bf(v.z); ol.z = f2bf(v.z - bf2f(oh.z));
    oh.w = f2bf(v.w); ol.w = f2bf(v.w - bf2f(oh.w));
    ((ushort4*)dh)[i] = oh;
    ((ushort4*)dl)[i] = ol;
}

// [Z][R][Cc] f32 -> [Z][Cc][R] bf16 hi/lo transpose (R,Cc mult of 32)
__global__ __launch_bounds__(256) void xpose_cast2(const float* __restrict__ src,
                                                   unsigned short* __restrict__ dh,
                                                   unsigned short* __restrict__ dl,
                                                   int R, int Cc)
{
    __shared__ float tile[32][33];
    const int z = blockIdx.z;
    const float* s = src + (long long)z * R * Cc;
    const long long zb = (long long)z * R * Cc;
    const int c0 = blockIdx.x * 32, r0 = blockIdx.y * 32;
    const int tc = threadIdx.x & 31, tr = threadIdx.x >> 5;
    #pragma unroll
    for (int q = 0; q < 4; ++q)
        tile[tr + q * 8][tc] = s[(long long)(r0 + tr + q * 8) * Cc + c0 + tc];
    __syncthreads();
    #pragma unroll
    for (int q = 0; q < 4; ++q) {
        float v = tile[tc][tr + q * 8];
        long long o = zb + (long long)(c0 + tr + q * 8) * R + r0 + tc;
        unsigned short h = f2bf(v);
        dh[o] = h;
        dl[o] = f2bf(v - bf2f(h));
    }
}

// x [512][1024] f32 -> X32 [1024][512] f32 + Xb hi/lo [1024][512] bf16
__global__ __launch_bounds__(256) void xpose_x2(const float* __restrict__ x,
                                                float* __restrict__ X32,
                                                unsigned short* __restrict__ Xh,
                                                unsigned short* __restrict__ Xl)
{
    __shared__ float tile[32][33];
    const int t0 = blockIdx.x * 32;
    const int c0 = blockIdx.y * 32;
    const int tc = threadIdx.x & 31, tr = threadIdx.x >> 5;
    #pragma unroll
    for (int q = 0; q < 4; ++q)
        tile[tr + q * 8][tc] = x[(long long)(c0 + tr + q * 8) * 1024 + t0 + tc];
    __syncthreads();
    #pragma unroll
    for (int q = 0; q < 4; ++q) {
        int tok = t0 + tr + q * 8, c = c0 + tc;
        float v = tile[tc][tr + q * 8];
        long long o = (long long)tok * 512 + c;
        X32[o] = v;
        unsigned short h = f2bf(v);
        Xh[o] = h;
        Xl[o] = f2bf(v - bf2f(h));
    }
}

// V^T hi/lo: QKV [1024][1536] cols 1024..1535 -> VT [512][1024]
__global__ __launch_bounds__(256) void vt_xpose2(const unsigned short* __restrict__ Qh,
                                                 const unsigned short* __restrict__ Ql,
                                                 unsigned short* __restrict__ VTh,
                                                 unsigned short* __restrict__ VTl)
{
    __shared__ unsigned short th[32][34];
    __shared__ unsigned short tl[32][34];
    const int c0 = blockIdx.x * 32;
    const int r0 = blockIdx.y * 32;
    const int tc = threadIdx.x & 31, tr = threadIdx.x >> 5;
    #pragma unroll
    for (int q = 0; q < 4; ++q) {
        long long o = (long long)(r0 + tr + q * 8) * 1536 + 1024 + c0 + tc;
        th[tr + q * 8][tc] = Qh[o];
        tl[tr + q * 8][tc] = Ql[o];
    }
    __syncthreads();
    #pragma unroll
    for (int q = 0; q < 4; ++q) {
        long long o = (long long)(c0 + tr + q * 8) * 1024 + r0 + tc;
        VTh[o] = th[tc][tr + q * 8];
        VTl[o] = tl[tc][tr + q * 8];
    }
}

// softmax over 1024 rows, f32 in -> bf16 hi/lo out
__global__ __launch_bounds__(256) void softmax_bf2(const float* __restrict__ S,
                                                   unsigned short* __restrict__ Ph,
                                                   unsigned short* __restrict__ Pl)
{
    __shared__ float rmax[4], rsum[4];
    const long long base = (long long)blockIdx.x * 1024;
    const int t = threadIdx.x;
    float4 v = *(const float4*)(S + base + t * 4);
    float mx = fmaxf(fmaxf(v.x, v.y), fmaxf(v.z, v.w));
    #pragma unroll
    for (int o = 32; o > 0; o >>= 1) mx = fmaxf(mx, __shfl_down(mx, o));
    if ((t & 63) == 0) rmax[t >> 6] = mx;
    __syncthreads();
    float m4 = fmaxf(fmaxf(rmax[0], rmax[1]), fmaxf(rmax[2], rmax[3]));
    v.x = expf(v.x - m4); v.y = expf(v.y - m4);
    v.z = expf(v.z - m4); v.w = expf(v.w - m4);
    float sm = v.x + v.y + v.z + v.w;
    #pragma unroll
    for (int o = 32; o > 0; o >>= 1) sm += __shfl_down(sm, o);
    if ((t & 63) == 0) rsum[t >> 6] = sm;
    __syncthreads();
    float inv = 1.f / (rsum[0] + rsum[1] + rsum[2] + rsum[3]);
    float p0 = v.x * inv, p1 = v.y * inv, p2 = v.z * inv, p3 = v.w * inv;
    ushort4 oh, ol;
    oh.x = f2bf(p0); ol.x = f2bf(p0 - bf2f(oh.x));
    oh.y = f2bf(p1); ol.y = f2bf(p1 - bf2f(oh.y));
    oh.z = f2bf(p2); ol.z = f2bf(p2 - bf2f(oh.z));
    oh.w = f2bf(p3); ol.w = f2bf(p3 - bf2f(oh.w));
    *(ushort4*)(Ph + base + t * 4) = oh;
    *(ushort4*)(Pl + base + t * 4) = ol;
}

// nearest grid_sample from token-major X [1024][512] -> XS [512][50][50]
__global__ __launch_bounds__(256) void grid_sample_t(const float* __restrict__ X,
                                                     float* __restrict__ XS)
{
    int idx = blockIdx.x * 256 + threadIdx.x;
    if (idx >= 512 * 2500) return;
    int ij = idx % 2500;
    int c = idx / 2500;
    int i = ij / 50, j = ij - i * 50;
    float vy = -49.f + 2.f * i;
    float gy = (vy + 51.2f) / 102.4f * 2.f - 1.f;
    float fy = ((gy + 1.f) * 32.f - 1.f) * 0.5f;
    int iy = (int)roundf(fy);
    bool oky = (iy >= 0) && (iy < 32);
    iy = min(max(iy, 0), 31);
    float vx = -49.f + 2.f * j;
    float gx = (vx + 51.2f) / 102.4f * 2.f - 1.f;
    float fx = ((gx + 1.f) * 32.f - 1.f) * 0.5f;
    int ix = (int)roundf(fx);
    bool okx = (ix >= 0) && (ix < 32);
    ix = min(max(ix, 0), 31);
    int tok = iy * 32 + ix;
    XS[idx] = (oky && okx) ? X[(long long)tok * 512 + c] : 0.f;
}

// pixel shuffle r=2: UP (2048,50,50) -> U (512,100,100)
__global__ __launch_bounds__(256) void pixshuf(const float* __restrict__ up, float* __restrict__ u)
{
    int idx = blockIdx.x * 256 + threadIdx.x;
    if (idx >= 512 * 100 * 100) return;
    int ow = idx % 100;
    int tmp = idx / 100;
    int oh = tmp % 100;
    int c = tmp / 100;
    int h = oh >> 1, r1 = oh & 1;
    int w = ow >> 1, r2 = ow & 1;
    u[idx] = up[(c * 4 + r1 * 2 + r2) * 2500 + h * 50 + w];
}

__global__ __launch_bounds__(256) void bnprep(
    const float* g1, const float* b1, const float* m1, const float* v1,
    const float* g2, const float* b2, const float* m2, const float* v2,
    float* sc1, float* bi1, float* sc2, float* bi2)
{
    int c = blockIdx.x * 256 + threadIdx.x;
    if (c >= 512) return;
    float s1 = g1[c] * rsqrtf(v1[c] + 1e-5f);
    sc1[c] = s1; bi1[c] = b1[c] - m1[c] * s1;
    float s2 = g2[c] * rsqrtf(v2[c] + 1e-5f);
    sc2[c] = s2; bi2[c] = b2[c] - m2[c] * s2;
}

// 1x1 conv (512->6) + sigmoid, fp32
__global__ __launch_bounds__(256) void conv1x1_sig(
    const float* __restrict__ in, const float* __restrict__ w,
    const float* __restrict__ b, float* __restrict__ out)
{
    int idx = blockIdx.x * 256 + threadIdx.x;
    if (idx >= 60000) return;
    int m = idx % 10000;
    int co = idx / 10000;
    float s = b[co];
    const float* wr = w + co * 512;
    for (int ci = 0; ci < 512; ++ci)
        s = fmaf(in[ci * 10000 + m], wr[ci], s);
    out[idx] = 1.f / (1.f + expf(-s));
}

// ---------------------------------------------------------------------------
extern "C" void kernel_launch(void* const* d_in, const int* in_sizes, int n_in,
                              void* d_out, int out_size, void* d_ws, size_t ws_size,
                              hipStream_t stream)
{
    const float* x      = (const float*)d_in[0];
    const float* qkv_w  = (const float*)d_in[1];
    const float* proj_w = (const float*)d_in[2];
    const float* proj_b = (const float*)d_in[3];
    const float* head_w = (const float*)d_in[4];
    const float* head_b = (const float*)d_in[5];
    const float* body_w = (const float*)d_in[6];
    const float* body_b = (const float*)d_in[7];
    const float* btail_w= (const float*)d_in[8];
    const float* btail_b= (const float*)d_in[9];
    const float* up_w   = (const float*)d_in[10];
    const float* up_b   = (const float*)d_in[11];
    const float* tail_w = (const float*)d_in[12];
    const float* tail_b = (const float*)d_in[13];
    const float* c1_w   = (const float*)d_in[14];
    const float* bn1_g  = (const float*)d_in[15];
    const float* bn1_b  = (const float*)d_in[16];
    const float* bn1_m  = (const float*)d_in[17];
    const float* bn1_v  = (const float*)d_in[18];
    const float* c2_w   = (const float*)d_in[19];
    const float* bn2_g  = (const float*)d_in[20];
    const float* bn2_b  = (const float*)d_in[21];
    const float* bn2_m  = (const float*)d_in[22];
    const float* bn2_v  = (const float*)d_in[23];
    const float* c3_w   = (const float*)d_in[24];
    const float* c3_b   = (const float*)d_in[25];

    char* base = (char*)d_ws;
    // ---- Phase A (attention) arena, byte offsets ----
    float*          S    = (float*)(base + 0);                 // 8M f32
    unsigned short* P_h  = (unsigned short*)(base + 33554432); // 8M bf16
    unsigned short* P_l  = (unsigned short*)(base + 50331648);
    unsigned short* Q_h  = (unsigned short*)(base + 67108864); // 1024x1536
    unsigned short* Q_l  = (unsigned short*)(base + 70254592);
    unsigned short* VT_h = (unsigned short*)(base + 73400320); // 512x1024
    unsigned short* VT_l = (unsigned short*)(base + 74448896);
    unsigned short* qw_h = (unsigned short*)(base + 75497472); // 8x1536x512
    unsigned short* qw_l = (unsigned short*)(base + 88080384);
    unsigned short* pw_h = (unsigned short*)(base + 100663296);// 8x512x512
    unsigned short* pw_l = (unsigned short*)(base + 104857600);
    unsigned short* O_h  = (unsigned short*)(base + 109051904);// 1024x512
    unsigned short* O_l  = (unsigned short*)(base + 110100480);
    float*          X32b = (float*)(base + 111149056);         // 1024x512 f32
    unsigned short* X_h  = (unsigned short*)(base + 113246208);
    unsigned short* X_l  = (unsigned short*)(base + 114294784);
    float*          X32a = (float*)(base + 115343360);         // survives to grid_sample
    // ---- Phase B (conv) arena, reuses [0, ...) — attention scratch dead ----
    unsigned short* COLh = (unsigned short*)(base + 0);         // 2560x4608
    unsigned short* COLl = (unsigned short*)(base + 23592960);
    unsigned short* WB_h = (unsigned short*)(base + 47185920);  // 2048x4608
    unsigned short* WB_l = (unsigned short*)(base + 66060288);
    float* XS = (float*)(base + 84934656);   // 512x2500
    float* Hh = (float*)(base + 90054656);
    float* T_ = (float*)(base + 95174656);
    float* R_ = (float*)(base + 100294656);
    float* R2 = (float*)(base + 105414656);
    float* UP = (float*)(base + 110534656);  // 2048x2500
    float* U_ = (float*)(base + 131014656);  // 512x10000
    float* Y_ = XS;                          // alias XS..R_ (dead by tail conv)
    float* Z1 = UP;                          // alias (UP dead after pixshuf)
    float* Z2 = U_;                          // alias (U_ dead after tail conv)
    float* SC1 = (float*)(base + 151494656);
    float* BI1 = SC1 + 512;
    float* SC2 = BI1 + 512;
    float* BI2 = SC2 + 512;

    const float scale = 0.044194173824159216f;  // 512^-0.5

    // ---- prep ----
    xpose_cast2<<<dim3(48, 16, 8), 256, 0, stream>>>(qkv_w, qw_h, qw_l, 512, 1536);
    xpose_cast2<<<dim3(16, 16, 8), 256, 0, stream>>>(proj_w, pw_h, pw_l, 512, 512);
    xpose_x2<<<dim3(32, 16), 256, 0, stream>>>(x, X32a, X_h, X_l);

    // ---- 8 self-attention blocks ----
    for (int i = 0; i < 8; ++i) {
        float* Xold = (i % 2 == 0) ? X32a : X32b;
        float* Xnew = (i % 2 == 0) ? X32b : X32a;
        // qkv: [1024][1536] hi/lo
        gemm3_nt<64, 128, 1, 4><<<dim3(12, 16, 1), 256, 0, stream>>>(
            X_h, X_l, 512, 0, qw_h + (long long)i * 786432, qw_l + (long long)i * 786432, 512, 0,
            nullptr, Q_h, Q_l, 1536, 0, nullptr, 1024, 1536, 512, 1.f,
            nullptr, nullptr, nullptr, 0);
        // scores per head -> S f32
        gemm3_nt<128, 128, 2, 2><<<dim3(8, 8, 8), 256, 0, stream>>>(
            Q_h, Q_l, 1536, 64, Q_h + 512, Q_l + 512, 1536, 64,
            S, nullptr, nullptr, 1024, 1048576, nullptr, 1024, 1024, 64, scale,
            nullptr, nullptr, nullptr, 0);
        softmax_bf2<<<8192, 256, 0, stream>>>(S, P_h, P_l);
        vt_xpose2<<<dim3(16, 32), 256, 0, stream>>>(Q_h, Q_l, VT_h, VT_l);
        // PV -> O hi/lo [1024][512]
        gemm3_nt<128, 64, 2, 2><<<dim3(1, 8, 8), 256, 0, stream>>>(
            P_h, P_l, 1024, 1048576, VT_h, VT_l, 1024, 65536,
            nullptr, O_h, O_l, 512, 64, nullptr, 1024, 64, 1024, 1.f,
            nullptr, nullptr, nullptr, 0);
        // proj + residual -> Xnew f32 + X hi/lo bf16
        gemm3_nt<64, 128, 1, 4><<<dim3(4, 16, 1), 256, 0, stream>>>(
            O_h, O_l, 512, 0, pw_h + (long long)i * 262144, pw_l + (long long)i * 262144, 512, 0,
            Xnew, X_h, X_l, 512, 0, Xold, 1024, 512, 512, 1.f,
            nullptr, nullptr, proj_b + i * 512, 0);
    }
    // final X in X32a (layer 7 writes X32a)

    // ---- BEV grid transform ----
    grid_sample_t<<<DIV_UP(1280000, 256), 256, 0, stream>>>(X32a, XS);

    // ---- conv3x3 via split im2col + split GEMM ----
    auto conv = [&](const float* in, const float* wsrc, const float* bias,
                    const float* scl, const float* resid, int relu,
                    float* out, int Cout, int H, int W) {
        int HW = H * W;
        int n4 = Cout * 4608 / 4;
        castbf2<<<DIV_UP(n4, 256), 256, 0, stream>>>(wsrc, WB_h, WB_l, n4);
        int slice = HW > 2560 ? 2560 : HW;
        for (int p0 = 0; p0 < HW; p0 += slice) {
            int np = HW - p0 < slice ? HW - p0 : slice;
            im2col2<<<np, 256, 0, stream>>>(in, COLh, COLl, H, W, p0);
            if (Cout == 2048) {
                gemm3_nt<128, 128, 2, 2><<<dim3(DIV_UP(np, 128), 16, 1), 256, 0, stream>>>(
                    WB_h, WB_l, 4608, 0, COLh, COLl, 4608, 0,
                    out + p0, nullptr, nullptr, HW, 0, resid ? resid + p0 : nullptr,
                    Cout, np, 4608, 1.f, bias, scl, nullptr, relu);
            } else {
                gemm3_nt<64, 128, 1, 4><<<dim3(DIV_UP(np, 128), 8, 1), 256, 0, stream>>>(
                    WB_h, WB_l, 4608, 0, COLh, COLl, 4608, 0,
                    out + p0, nullptr, nullptr, HW, 0, resid ? resid + p0 : nullptr,
                    Cout, np, 4608, 1.f, bias, scl, nullptr, relu);
            }
        }
    };

    // EDSR
    conv(XS, head_w, head_b, nullptr, nullptr, 0, Hh, 512, 50, 50);
    for (int i = 0; i < 8; ++i) {
        const float* rin = (i == 0) ? Hh : R_;
        conv(rin, body_w + (long long)(2 * i) * 2359296, body_b + 2 * i * 512,
             nullptr, nullptr, 1, T_, 512, 50, 50);
        conv(T_, body_w + (long long)(2 * i + 1) * 2359296, body_b + (2 * i + 1) * 512,
             nullptr, rin, 0, R_, 512, 50, 50);
    }
    conv(R_, btail_w, btail_b, nullptr, Hh, 0, R2, 512, 50, 50);
    conv(R2, up_w, up_b, nullptr, nullptr, 0, UP, 2048, 50, 50);
    pixshuf<<<DIV_UP(5120000, 256), 256, 0, stream>>>(UP, U_);
    conv(U_, tail_w, tail_b, nullptr, nullptr, 0, Y_, 512, 100, 100);

    // classifier
    bnprep<<<2, 256, 0, stream>>>(bn1_g, bn1_b, bn1_m, bn1_v,
                                  bn2_g, bn2_b, bn2_m, bn2_v, SC1, BI1, SC2, BI2);
    conv(Y_, c1_w, BI1, SC1, nullptr, 1, Z1, 512, 100, 100);
    conv(Z1, c2_w, BI2, SC2, nullptr, 1, Z2, 512, 100, 100);
    conv1x1_sig<<<DIV_UP(60000, 256), 256, 0, stream>>>(Z2, c3_w, c3_b, (float*)d_out);
}